// Round 6
// baseline (2954.404 us; speedup 1.0000x reference)
//
#include <hip/hip_runtime.h>
#include <hip/hip_fp16.h>

// ---------------------------------------------------------------------------
// HypergraphNet: out = conv2(relu(conv1(x)))
// conv(x) = D^-1 H diag(w) B^-1 H^T (x @ W) + b
// N = E = 65536, F = 128, nnz = 2^20.
//
// Round-5: fine sort (passC) fused into the gather. Records bucketed only to
// 64-row granularity; k_bgather reads its bucket's records densely and
// accumulates rows into an LDS fp32 tile (ds_add_f32, padded stride 132).
// cnt/deg computed in-LDS; scale+bias+relu fused in epilogue.
//   k_prep_w  : W1,W2 -> half W^T [n][k]
//   k_passA   : 1024-bin coarse histogram (key>>6), LDS-privatized
//   k_scan    : exclusive scan of 1024 bins -> bases + cursors (2 blocks)
//   k_passB   : block-local binning, one global atomic per bin per block,
//               dense 4B records ((key&63)<<16 | srcIdx)
//   k_gemm<TA>: MFMA 16x16x32_f16 (unchanged from R4)
//   k_bgather : 1 block per 64-row bucket; wave-wide row gather (unroll 4),
//               LDS fp32 accumulate; fused scale/bias/relu; f16 or f32 out
// ---------------------------------------------------------------------------

typedef unsigned int uint32;
typedef _Float16 f16;
typedef _Float16 f16x8 __attribute__((ext_vector_type(8)));
typedef float f32x4 __attribute__((ext_vector_type(4)));

#define B_ROWS 64
#define ACC_STRIDE 132   // 132 mod 32 = 4 -> consecutive rows rotate 4 banks

__global__ __launch_bounds__(256) void k_prep_w(const float* __restrict__ W1,
                                                const float* __restrict__ W2,
                                                f16* __restrict__ W1t,
                                                f16* __restrict__ W2t) {
  const float* W = (blockIdx.x & 1) ? W2 : W1;
  f16* Wt = (blockIdx.x & 1) ? W2t : W1t;
  const int base = (blockIdx.x >> 1) * 4096;
#pragma unroll
  for (int it = 0; it < 16; ++it) {
    int idx = base + it * 256 + threadIdx.x;
    int k = idx >> 7, n = idx & 127;
    Wt[n * 128 + k] = (f16)W[k * 128 + n];
  }
}

__global__ __launch_bounds__(256) void k_passA(const int* __restrict__ nidx,
                                               const int* __restrict__ eidx,
                                               int* __restrict__ cnt_e,
                                               int* __restrict__ cnt_n,
                                               int nnz) {
  __shared__ int he[1024], hn[1024];
  const int tid = threadIdx.x;
  for (int i = tid; i < 1024; i += 256) { he[i] = 0; hn[i] = 0; }
  __syncthreads();
  const int base = blockIdx.x * 4096;
#pragma unroll
  for (int it = 0; it < 16; ++it) {
    int i = base + it * 256 + tid;
    if (i < nnz) {
      atomicAdd(&he[eidx[i] >> 6], 1);
      atomicAdd(&hn[nidx[i] >> 6], 1);
    }
  }
  __syncthreads();
  for (int i = tid; i < 1024; i += 256) {
    if (he[i]) atomicAdd(&cnt_e[i], he[i]);
    if (hn[i]) atomicAdd(&cnt_n[i], hn[i]);
  }
}

// 2 blocks (e-side / n-side), 1024 threads: exclusive scan -> base + cursor.
__global__ __launch_bounds__(1024) void k_scan(const int* __restrict__ cnt_e,
                                               int* __restrict__ base_e,
                                               int* __restrict__ cur_e,
                                               const int* __restrict__ cnt_n,
                                               int* __restrict__ base_n,
                                               int* __restrict__ cur_n) {
  __shared__ int s[1024];
  const int tid = threadIdx.x;
  const int* cnt = blockIdx.x ? cnt_n : cnt_e;
  int* base = blockIdx.x ? base_n : base_e;
  int* cur = blockIdx.x ? cur_n : cur_e;
  int v = cnt[tid];
  s[tid] = v;
  __syncthreads();
  for (int off = 1; off < 1024; off <<= 1) {
    int t = (tid >= off) ? s[tid - off] : 0;
    __syncthreads();
    s[tid] += t;
    __syncthreads();
  }
  base[tid] = s[tid] - v;
  cur[tid] = s[tid] - v;
  if (tid == 1023) base[1024] = s[1023];
}

// Bin entries into 1024 coarse buckets as packed records ((key&63)<<16|val).
__global__ __launch_bounds__(256) void k_passB(const int* __restrict__ nidx,
                                               const int* __restrict__ eidx,
                                               int* __restrict__ cur_e,
                                               int* __restrict__ cur_n,
                                               uint32* __restrict__ rec_e,
                                               uint32* __restrict__ rec_n,
                                               int nnz) {
  __shared__ int hist[1024];
  __shared__ int gbase[1024];
  __shared__ int lcur[1024];
  const int tid = threadIdx.x;
  const int side = blockIdx.x >> 8;
  const int blk = blockIdx.x & 255;
  const int* keyp = side ? nidx : eidx;
  const int* valp = side ? eidx : nidx;
  int* cursor = side ? cur_n : cur_e;
  uint32* rec = side ? rec_n : rec_e;

  for (int i = tid; i < 1024; i += 256) hist[i] = 0;
  __syncthreads();
  const int base = blk * 4096;
#pragma unroll
  for (int it = 0; it < 16; ++it) {
    int i = base + it * 256 + tid;
    if (i < nnz) atomicAdd(&hist[keyp[i] >> 6], 1);
  }
  __syncthreads();
  for (int i = tid; i < 1024; i += 256) {
    int h = hist[i];
    gbase[i] = h ? atomicAdd(&cursor[i], h) : 0;
    lcur[i] = 0;
  }
  __syncthreads();
#pragma unroll
  for (int it = 0; it < 16; ++it) {
    int i = base + it * 256 + tid;
    if (i < nnz) {
      int key = keyp[i], val = valp[i];
      int d = key >> 6;
      int p = atomicAdd(&lcur[d], 1);
      rec[gbase[d] + p] = ((uint32)(key & 63) << 16) | (uint32)val;
    }
  }
}

// C[M,128] = A[M,128] @ B[128,128] via MFMA f16, C stored half. (R4, working)
template <typename TA>
__global__ __launch_bounds__(256) void k_gemm(const TA* __restrict__ A,
                                              const f16* __restrict__ Bt,
                                              f16* __restrict__ C) {
  __shared__ f16 As[64][136];
  __shared__ f16 Bs[128][136];
  const int tid = threadIdx.x;
  const size_t m0 = (size_t)blockIdx.x * 64;

  {  // stage A: 4 threads/row, 32 halves each
    const int row = tid >> 2, seg = tid & 3;
    if constexpr (sizeof(TA) == 4) {
      const float4* ap = reinterpret_cast<const float4*>((const float*)A + (m0 + row) * 128 + seg * 32);
#pragma unroll
      for (int i = 0; i < 8; ++i) {
        float4 v = ap[i];
        union { f16 h[4]; uint2 u; } pk;
        pk.h[0] = (f16)v.x; pk.h[1] = (f16)v.y;
        pk.h[2] = (f16)v.z; pk.h[3] = (f16)v.w;
        *reinterpret_cast<uint2*>(&As[row][seg * 32 + i * 4]) = pk.u;
      }
    } else {
      const uint4* ap = reinterpret_cast<const uint4*>((const f16*)A + (m0 + row) * 128 + seg * 32);
#pragma unroll
      for (int i = 0; i < 4; ++i)
        *reinterpret_cast<uint4*>(&As[row][seg * 32 + i * 8]) = ap[i];
    }
  }
  {  // stage B: 2 threads/n-row, 64 halves each = 8 x uint4
    const int n = tid >> 1, seg = tid & 1;
    const uint4* bp = reinterpret_cast<const uint4*>(Bt + n * 128 + seg * 64);
#pragma unroll
    for (int i = 0; i < 8; ++i)
      *reinterpret_cast<uint4*>(&Bs[n][seg * 64 + i * 8]) = bp[i];
  }
  __syncthreads();

  const int wave = tid >> 6, lane = tid & 63;
  const int wm = wave >> 1, wn = wave & 1;
  const int fr = lane & 15, quad = lane >> 4;

  f32x4 acc[2][4];
#pragma unroll
  for (int i = 0; i < 2; ++i)
#pragma unroll
    for (int j = 0; j < 4; ++j) acc[i][j] = (f32x4){0.f, 0.f, 0.f, 0.f};

#pragma unroll
  for (int kk = 0; kk < 4; ++kk) {
    f16x8 af[2], bf[4];
#pragma unroll
    for (int i = 0; i < 2; ++i)
      af[i] = *reinterpret_cast<const f16x8*>(&As[wm * 32 + i * 16 + fr][kk * 32 + quad * 8]);
#pragma unroll
    for (int j = 0; j < 4; ++j)
      bf[j] = *reinterpret_cast<const f16x8*>(&Bs[wn * 64 + j * 16 + fr][kk * 32 + quad * 8]);
#pragma unroll
    for (int i = 0; i < 2; ++i)
#pragma unroll
      for (int j = 0; j < 4; ++j)
        acc[i][j] = __builtin_amdgcn_mfma_f32_16x16x32_f16(af[i], bf[j], acc[i][j], 0, 0, 0);
  }

#pragma unroll
  for (int i = 0; i < 2; ++i)
#pragma unroll
    for (int j = 0; j < 4; ++j)
#pragma unroll
      for (int r = 0; r < 4; ++r) {
        size_t row = m0 + wm * 32 + i * 16 + quad * 4 + r;
        int colc = wn * 64 + j * 16 + fr;
        C[row * 128 + colc] = (f16)acc[i][j][r];
      }
}

// One block per 64-row bucket. Waves stream the bucket's records (4 in
// flight), gather 256B fp16 rows wave-wide, accumulate fp32 in LDS.
// mode 0 (edge dest): deg=count, scale=w[dest]/cnt.
// mode 1 (node dest): deg=sum w[srcEdge], scale=1/deg; bias/relu/f32-out.
__global__ __launch_bounds__(256) void k_bgather(const uint32* __restrict__ src,
                                                 void* __restrict__ dst,
                                                 const uint32* __restrict__ rec,
                                                 const int* __restrict__ base,
                                                 const float* __restrict__ w,
                                                 const float* __restrict__ bias,
                                                 int mode, int relu, int out_f32) {
  __shared__ float acc[B_ROWS][ACC_STRIDE];
  __shared__ float deg[B_ROWS];
  const int tid = threadIdx.x;
  const int b = blockIdx.x;
  {
    float4 z = {0.f, 0.f, 0.f, 0.f};
    float4* ap = (float4*)&acc[0][0];
    for (int i = tid; i < B_ROWS * ACC_STRIDE / 4; i += 256) ap[i] = z;
    if (tid < B_ROWS) deg[tid] = 0.f;
  }
  __syncthreads();

  const int beg = base[b], end = base[b + 1];
  const int wave = tid >> 6, lane = tid & 63;
  for (int j0 = beg + wave * 4; j0 < end; j0 += 16) {
    int m = end - j0;
    m = m > 4 ? 4 : m;
    uint32 r[4], v[4];
#pragma unroll
    for (int k = 0; k < 4; ++k) r[k] = rec[j0 + (k < m ? k : 0)];
#pragma unroll
    for (int k = 0; k < 4; ++k) v[k] = src[(r[k] & 0xffffu) * 64 + lane];
    if (lane == 0) {
#pragma unroll
      for (int k = 0; k < 4; ++k)
        if (k < m) atomicAdd(&deg[r[k] >> 16], mode ? w[r[k] & 0xffffu] : 1.0f);
    }
#pragma unroll
    for (int k = 0; k < 4; ++k)
      if (k < m) {
        union { uint32 u; f16 h[2]; } cv;
        cv.u = v[k];
        int d = r[k] >> 16;
        atomicAdd(&acc[d][lane * 2], (float)cv.h[0]);
        atomicAdd(&acc[d][lane * 2 + 1], (float)cv.h[1]);
      }
  }
  __syncthreads();

  // epilogue: thread -> (row = tid>>2, 32-col segment = tid&3)
  const int row = tid >> 2, seg = tid & 3;
  const int gdest = b * B_ROWS + row;
  const float dv = deg[row];
  float scale;
  if (mode == 0)
    scale = dv > 0.f ? w[gdest] / dv : 0.f;
  else
    scale = dv > 0.f ? 1.f / dv : 0.f;

  if (out_f32) {
    float4* dp = (float4*)((float*)dst + (size_t)gdest * 128 + seg * 32);
#pragma unroll
    for (int i = 0; i < 8; ++i) {
      float4 a = *(float4*)&acc[row][seg * 32 + i * 4];
      a.x *= scale; a.y *= scale; a.z *= scale; a.w *= scale;
      if (bias) {
        const float4 bb = *(const float4*)&bias[seg * 32 + i * 4];
        a.x += bb.x; a.y += bb.y; a.z += bb.z; a.w += bb.w;
      }
      if (relu) {
        a.x = fmaxf(a.x, 0.f); a.y = fmaxf(a.y, 0.f);
        a.z = fmaxf(a.z, 0.f); a.w = fmaxf(a.w, 0.f);
      }
      dp[i] = a;
    }
  } else {
    uint2* hp = (uint2*)((f16*)dst + (size_t)gdest * 128 + seg * 32);
#pragma unroll
    for (int i = 0; i < 8; ++i) {
      float4 a = *(float4*)&acc[row][seg * 32 + i * 4];
      a.x *= scale; a.y *= scale; a.z *= scale; a.w *= scale;
      if (bias) {
        const float4 bb = *(const float4*)&bias[seg * 32 + i * 4];
        a.x += bb.x; a.y += bb.y; a.z += bb.z; a.w += bb.w;
      }
      if (relu) {
        a.x = fmaxf(a.x, 0.f); a.y = fmaxf(a.y, 0.f);
        a.z = fmaxf(a.z, 0.f); a.w = fmaxf(a.w, 0.f);
      }
      union { f16 h[4]; uint2 u; } pk;
      pk.h[0] = (f16)a.x; pk.h[1] = (f16)a.y;
      pk.h[2] = (f16)a.z; pk.h[3] = (f16)a.w;
      hp[i] = pk.u;
    }
  }
}

extern "C" void kernel_launch(void* const* d_in, const int* in_sizes, int n_in,
                              void* d_out, int out_size, void* d_ws, size_t ws_size,
                              hipStream_t stream) {
  const float* x  = (const float*)d_in[0];
  const int* nidx = (const int*)d_in[1];
  const int nnz   = in_sizes[1] / 2;
  const int* eidx = nidx + nnz;
  const float* w  = (const float*)d_in[2];
  const float* W1 = (const float*)d_in[3];
  const float* b1 = (const float*)d_in[4];
  const float* W2 = (const float*)d_in[5];
  const float* b2 = (const float*)d_in[6];
  float* out = (float*)d_out;

  const int N = in_sizes[0] / 128;  // 65536 nodes
  const size_t NB = (size_t)N * 128;

  // workspace layout
  f16* f0h      = (f16*)d_ws;               // [N,128] half feature buf A
  f16* f1h      = f0h + NB;                 // [N,128] half feature buf B
  int* cnt_e    = (int*)(f1h + NB);         // [1024]
  int* cnt_n    = cnt_e + 1024;             // [1024]
  int* base_e   = cnt_n + 1024;             // [1025]
  int* base_n   = base_e + 1025;            // [1025]
  int* cur_e    = base_n + 1025;            // [1024]
  int* cur_n    = cur_e + 1024;             // [1024]
  f16* W1t      = (f16*)(cur_n + 1024);     // [128,128]
  f16* W2t      = W1t + 128 * 128;          // [128,128]
  uint32* rec_e = (uint32*)(W2t + 128 * 128);  // [nnz] (persist both layers)
  uint32* rec_n = rec_e + nnz;                 // [nnz]

  const int gemm_grid = N / 64;
  const int bg_grid = N / B_ROWS;  // 1024 (N == E)

  // ---- weight prep + bucketed record build ----
  k_prep_w<<<8, 256, 0, stream>>>(W1, W2, W1t, W2t);
  hipMemsetAsync(cnt_e, 0, 2 * 1024 * sizeof(int), stream);
  k_passA<<<(nnz + 4095) / 4096, 256, 0, stream>>>(nidx, eidx, cnt_e, cnt_n, nnz);
  k_scan<<<2, 1024, 0, stream>>>(cnt_e, base_e, cur_e, cnt_n, base_n, cur_n);
  k_passB<<<512, 256, 0, stream>>>(nidx, eidx, cur_e, cur_n, rec_e, rec_n, nnz);

  // ---- layer 1 ----
  k_gemm<float><<<gemm_grid, 256, 0, stream>>>(x, W1t, f0h);       // f0h = half(x@W1)
  k_bgather<<<bg_grid, 256, 0, stream>>>((const uint32*)f0h, f1h, rec_e, base_e,
                                         w, nullptr, 0, 0, 0);     // f1h = e_feat
  k_bgather<<<bg_grid, 256, 0, stream>>>((const uint32*)f1h, f0h, rec_n, base_n,
                                         w, b1, 1, 1, 0);          // f0h = h

  // ---- layer 2 ----
  k_gemm<f16><<<gemm_grid, 256, 0, stream>>>(f0h, W2t, f1h);       // f1h = half(h@W2)
  k_bgather<<<bg_grid, 256, 0, stream>>>((const uint32*)f1h, f0h, rec_e, base_e,
                                         w, nullptr, 0, 0, 0);     // f0h = e_feat
  k_bgather<<<bg_grid, 256, 0, stream>>>((const uint32*)f0h, out, rec_n, base_n,
                                         w, b2, 1, 0, 1);          // out (fp32)
}

// Round 9
// 332.282 us; speedup vs baseline: 8.8913x; 8.8913x over previous
//
#include <hip/hip_runtime.h>
#include <hip/hip_fp16.h>

// ---------------------------------------------------------------------------
// HypergraphNet: out = conv2(relu(conv1(x)))
// conv(x) = D^-1 H diag(w) B^-1 H^T (x @ W) + b
// N = E = 65536, F = 128, nnz = 2^20.
//
// Round-8: hazard-hardened R4 (the fastest passing structure, 323 us).
// R6/R7 both flaked post-timing with disjoint changes -> race lives in the
// shared structure. Hardening:
//   * col arrays are uint32 (word-granular stores; no 32-bit word is ever
//     written by two blocks, killing cross-XCD partial-word byte-merge risk)
//   * rec buffers get dedicated workspace (no aliasing with feature bufs)
//   * coarse scan writes bases out-of-place (no in-place array update)
//   * passC is R4's single-pass scatter (R7 chunk ordering was neutral)
// Pipeline:
//   k_prep_w     : W1,W2 -> half W^T [n][k]
//   k_passA      : 256-bin coarse histogram (key>>8), LDS-privatized
//   k_coarse_scan: scan 256 bins -> bases + cursors (out-of-place)
//   k_passB      : single-read binning, block-local LDS reserve, dense recs
//   k_passC      : per-bucket finalize: rp, e_scale / d_inv, col (uint32)
//   k_gemm<TA>   : MFMA 16x16x32_f16
//   k_gather     : 16 lanes x 16B(half8) per row, unroll-4, fused
//                  scale/bias/relu; half or fp32 output
// ---------------------------------------------------------------------------

typedef unsigned int uint32;
typedef _Float16 f16;
typedef _Float16 f16x8 __attribute__((ext_vector_type(8)));
typedef float f32x4 __attribute__((ext_vector_type(4)));

__global__ __launch_bounds__(256) void k_prep_w(const float* __restrict__ W1,
                                                const float* __restrict__ W2,
                                                f16* __restrict__ W1t,
                                                f16* __restrict__ W2t) {
  const float* W = (blockIdx.x & 1) ? W2 : W1;
  f16* Wt = (blockIdx.x & 1) ? W2t : W1t;
  const int base = (blockIdx.x >> 1) * 4096;
#pragma unroll
  for (int it = 0; it < 16; ++it) {
    int idx = base + it * 256 + threadIdx.x;
    int k = idx >> 7, n = idx & 127;
    Wt[n * 128 + k] = (f16)W[k * 128 + n];
  }
}

__global__ __launch_bounds__(256) void k_passA(const int* __restrict__ nidx,
                                               const int* __restrict__ eidx,
                                               int* __restrict__ cnt_ce,
                                               int* __restrict__ cnt_cn,
                                               int nnz) {
  __shared__ int he[256], hn[256];
  const int tid = threadIdx.x;
  he[tid] = 0;
  hn[tid] = 0;
  __syncthreads();
  const int base = blockIdx.x * 4096;
#pragma unroll
  for (int it = 0; it < 16; ++it) {
    int i = base + it * 256 + tid;
    if (i < nnz) {
      atomicAdd(&he[eidx[i] >> 8], 1);
      atomicAdd(&hn[nidx[i] >> 8], 1);
    }
  }
  __syncthreads();
  atomicAdd(&cnt_ce[tid], he[tid]);
  atomicAdd(&cnt_cn[tid], hn[tid]);
}

// One block. Exclusive-scan both coarse count arrays -> OUT-OF-PLACE bases
// (be/bn separate from ce/cn) + cursors.
__global__ __launch_bounds__(256) void k_coarse_scan(const int* __restrict__ ce,
                                                     int* __restrict__ be,
                                                     int* __restrict__ cure,
                                                     const int* __restrict__ cn,
                                                     int* __restrict__ bn,
                                                     int* __restrict__ curn) {
  __shared__ int s[256];
  const int tid = threadIdx.x;
  int v = ce[tid];
  s[tid] = v;
  __syncthreads();
  for (int off = 1; off < 256; off <<= 1) {
    int t = (tid >= off) ? s[tid - off] : 0;
    __syncthreads();
    s[tid] += t;
    __syncthreads();
  }
  be[tid] = s[tid] - v;
  cure[tid] = s[tid] - v;
  if (tid == 255) be[256] = s[255];
  __syncthreads();
  v = cn[tid];
  s[tid] = v;
  __syncthreads();
  for (int off = 1; off < 256; off <<= 1) {
    int t = (tid >= off) ? s[tid - off] : 0;
    __syncthreads();
    s[tid] += t;
    __syncthreads();
  }
  bn[tid] = s[tid] - v;
  curn[tid] = s[tid] - v;
  if (tid == 255) bn[256] = s[255];
}

// Bin entries into coarse buckets as packed records (keylow<<16 | value).
// Input read EXACTLY ONCE, cached in registers between phases.
__global__ __launch_bounds__(256) void k_passB(const int* __restrict__ nidx,
                                               const int* __restrict__ eidx,
                                               int* __restrict__ cur_e,
                                               int* __restrict__ cur_n,
                                               uint32* __restrict__ rec_e,
                                               uint32* __restrict__ rec_n,
                                               int nnz) {
  __shared__ int hist[256];
  __shared__ int gbase[256];
  __shared__ int lcur[256];
  const int tid = threadIdx.x;
  const int side = blockIdx.x >> 8;
  const int blk = blockIdx.x & 255;
  const int* keyp = side ? nidx : eidx;
  const int* valp = side ? eidx : nidx;
  int* cursor = side ? cur_n : cur_e;
  uint32* rec = side ? rec_n : rec_e;

  hist[tid] = 0;
  __syncthreads();
  int key[16], val[16];
  const int base = blk * 4096;
#pragma unroll
  for (int it = 0; it < 16; ++it) {
    int i = base + it * 256 + tid;
    if (i < nnz) {
      key[it] = keyp[i];
      val[it] = valp[i];
      atomicAdd(&hist[key[it] >> 8], 1);
    } else {
      key[it] = -1;
    }
  }
  __syncthreads();
  {
    int h = hist[tid];
    gbase[tid] = h ? atomicAdd(&cursor[tid], h) : 0;
    lcur[tid] = 0;
  }
  __syncthreads();
#pragma unroll
  for (int it = 0; it < 16; ++it) {
    if (key[it] >= 0) {
      int d = key[it] >> 8;
      int p = atomicAdd(&lcur[d], 1);
      rec[gbase[d] + p] = ((uint32)(key[it] & 0xff) << 16) | (uint32)val[it];
    }
  }
}

// Finalize one coarse bucket: rp, scale, col (uint32 — word-granular).
__global__ __launch_bounds__(256) void k_passC(const uint32* __restrict__ rec_e,
                                               const uint32* __restrict__ rec_n,
                                               const int* __restrict__ be,
                                               const int* __restrict__ bn,
                                               const float* __restrict__ w,
                                               int* __restrict__ rp_e,
                                               int* __restrict__ rp_n,
                                               uint32* __restrict__ col_e,
                                               uint32* __restrict__ col_n,
                                               float* __restrict__ e_scale,
                                               float* __restrict__ d_inv) {
  __shared__ int hist[256];
  __shared__ int s[256];
  __shared__ int lcur[256];
  __shared__ float degf[256];
  const int tid = threadIdx.x;
  const int side = blockIdx.x >> 8;
  const int b = blockIdx.x & 255;
  const uint32* rec = side ? rec_n : rec_e;
  const int* bb = side ? bn : be;
  int* rp = side ? rp_n : rp_e;
  uint32* col = side ? col_n : col_e;

  const int beg = bb[b], end = bb[b + 1];
  hist[tid] = 0;
  degf[tid] = 0.f;
  __syncthreads();
  for (int j = beg + tid; j < end; j += 256) {
    uint32 r = rec[j];
    int d = r >> 16;
    atomicAdd(&hist[d], 1);
    if (side) atomicAdd(&degf[d], w[r & 0xffff]);
  }
  __syncthreads();
  int h = hist[tid];
  s[tid] = h;
  __syncthreads();
  for (int off = 1; off < 256; off <<= 1) {
    int t = (tid >= off) ? s[tid - off] : 0;
    __syncthreads();
    s[tid] += t;
    __syncthreads();
  }
  const int start = s[tid] - h;
  const int key = (b << 8) | tid;
  rp[key] = beg + start;
  if (tid == 255) rp[(b << 8) + 256] = end;
  if (side) {
    float d = degf[tid];
    d_inv[key] = d > 0.f ? 1.f / d : 0.f;
  } else {
    e_scale[key] = h > 0 ? w[key] / (float)h : 0.f;
  }
  lcur[tid] = start;
  __syncthreads();
  for (int j = beg + tid; j < end; j += 256) {
    uint32 r = rec[j];
    int d = r >> 16;
    int p = atomicAdd(&lcur[d], 1);
    col[beg + p] = r & 0xffffu;
  }
}

// C[M,128] = A[M,128] @ B[128,128] via MFMA f16, C stored half.
template <typename TA>
__global__ __launch_bounds__(256) void k_gemm(const TA* __restrict__ A,
                                              const f16* __restrict__ Bt,
                                              f16* __restrict__ C) {
  __shared__ f16 As[64][136];
  __shared__ f16 Bs[128][136];
  const int tid = threadIdx.x;
  const size_t m0 = (size_t)blockIdx.x * 64;

  {  // stage A: 4 threads/row, 32 halves each
    const int row = tid >> 2, seg = tid & 3;
    if constexpr (sizeof(TA) == 4) {
      const float4* ap = reinterpret_cast<const float4*>((const float*)A + (m0 + row) * 128 + seg * 32);
#pragma unroll
      for (int i = 0; i < 8; ++i) {
        float4 v = ap[i];
        union { f16 h[4]; uint2 u; } pk;
        pk.h[0] = (f16)v.x; pk.h[1] = (f16)v.y;
        pk.h[2] = (f16)v.z; pk.h[3] = (f16)v.w;
        *reinterpret_cast<uint2*>(&As[row][seg * 32 + i * 4]) = pk.u;
      }
    } else {
      const uint4* ap = reinterpret_cast<const uint4*>((const f16*)A + (m0 + row) * 128 + seg * 32);
#pragma unroll
      for (int i = 0; i < 4; ++i)
        *reinterpret_cast<uint4*>(&As[row][seg * 32 + i * 8]) = ap[i];
    }
  }
  {  // stage B: 2 threads/n-row, 64 halves each = 8 x uint4
    const int n = tid >> 1, seg = tid & 1;
    const uint4* bp = reinterpret_cast<const uint4*>(Bt + n * 128 + seg * 64);
#pragma unroll
    for (int i = 0; i < 8; ++i)
      *reinterpret_cast<uint4*>(&Bs[n][seg * 64 + i * 8]) = bp[i];
  }
  __syncthreads();

  const int wave = tid >> 6, lane = tid & 63;
  const int wm = wave >> 1, wn = wave & 1;
  const int fr = lane & 15, quad = lane >> 4;

  f32x4 acc[2][4];
#pragma unroll
  for (int i = 0; i < 2; ++i)
#pragma unroll
    for (int j = 0; j < 4; ++j) acc[i][j] = (f32x4){0.f, 0.f, 0.f, 0.f};

#pragma unroll
  for (int kk = 0; kk < 4; ++kk) {
    f16x8 af[2], bf[4];
#pragma unroll
    for (int i = 0; i < 2; ++i)
      af[i] = *reinterpret_cast<const f16x8*>(&As[wm * 32 + i * 16 + fr][kk * 32 + quad * 8]);
#pragma unroll
    for (int j = 0; j < 4; ++j)
      bf[j] = *reinterpret_cast<const f16x8*>(&Bs[wn * 64 + j * 16 + fr][kk * 32 + quad * 8]);
#pragma unroll
    for (int i = 0; i < 2; ++i)
#pragma unroll
      for (int j = 0; j < 4; ++j)
        acc[i][j] = __builtin_amdgcn_mfma_f32_16x16x32_f16(af[i], bf[j], acc[i][j], 0, 0, 0);
  }

  // C/D layout: col=lane&15, row=quad*4+reg (verified m89/m91)
#pragma unroll
  for (int i = 0; i < 2; ++i)
#pragma unroll
    for (int j = 0; j < 4; ++j)
#pragma unroll
      for (int r = 0; r < 4; ++r) {
        size_t row = m0 + wm * 32 + i * 16 + quad * 4 + r;
        int colc = wn * 64 + j * 16 + fr;
        C[row * 128 + colc] = (f16)acc[i][j][r];
      }
}

// 16 lanes x 16B (half8) per output row, unroll-4, fp32 accumulate.
__global__ __launch_bounds__(256) void k_gather(const uint4* __restrict__ src,
                                                void* __restrict__ dst,
                                                const int* __restrict__ rp,
                                                const uint32* __restrict__ col,
                                                const float* __restrict__ rscale,
                                                const float* __restrict__ bias,
                                                int relu, int out_f32, int nrows) {
  const int row = (blockIdx.x * 256 + threadIdx.x) >> 4;
  const int lane = threadIdx.x & 15;
  if (row >= nrows) return;
  const int beg = rp[row], end = rp[row + 1];
  float acc[8];
#pragma unroll
  for (int k = 0; k < 8; ++k) acc[k] = 0.f;
  union U { uint4 u; f16 h[8]; };
  int j = beg;
  for (; j + 3 < end; j += 4) {
    uint32 c0 = col[j], c1 = col[j + 1], c2 = col[j + 2], c3 = col[j + 3];
    U v0, v1, v2, v3;
    v0.u = src[(size_t)c0 * 16 + lane];
    v1.u = src[(size_t)c1 * 16 + lane];
    v2.u = src[(size_t)c2 * 16 + lane];
    v3.u = src[(size_t)c3 * 16 + lane];
#pragma unroll
    for (int k = 0; k < 8; ++k)
      acc[k] += ((float)v0.h[k] + (float)v1.h[k]) + ((float)v2.h[k] + (float)v3.h[k]);
  }
  for (; j < end; ++j) {
    U v;
    v.u = src[(size_t)col[j] * 16 + lane];
#pragma unroll
    for (int k = 0; k < 8; ++k) acc[k] += (float)v.h[k];
  }
  const float s = rscale[row];
#pragma unroll
  for (int k = 0; k < 8; ++k) acc[k] *= s;
  if (bias) {
    const float4* bp = reinterpret_cast<const float4*>(bias) + lane * 2;
    float4 b0 = bp[0], b1 = bp[1];
    acc[0] += b0.x; acc[1] += b0.y; acc[2] += b0.z; acc[3] += b0.w;
    acc[4] += b1.x; acc[5] += b1.y; acc[6] += b1.z; acc[7] += b1.w;
    if (relu) {
#pragma unroll
      for (int k = 0; k < 8; ++k) acc[k] = fmaxf(acc[k], 0.f);
    }
  }
  if (out_f32) {
    float4* dp = (float4*)dst + (size_t)row * 32 + lane * 2;
    dp[0] = make_float4(acc[0], acc[1], acc[2], acc[3]);
    dp[1] = make_float4(acc[4], acc[5], acc[6], acc[7]);
  } else {
    U o;
#pragma unroll
    for (int k = 0; k < 8; ++k) o.h[k] = (f16)acc[k];
    ((uint4*)dst)[(size_t)row * 16 + lane] = o.u;
  }
}

extern "C" void kernel_launch(void* const* d_in, const int* in_sizes, int n_in,
                              void* d_out, int out_size, void* d_ws, size_t ws_size,
                              hipStream_t stream) {
  const float* x  = (const float*)d_in[0];
  const int* nidx = (const int*)d_in[1];
  const int nnz   = in_sizes[1] / 2;
  const int* eidx = nidx + nnz;
  const float* w  = (const float*)d_in[2];
  const float* W1 = (const float*)d_in[3];
  const float* b1 = (const float*)d_in[4];
  const float* W2 = (const float*)d_in[5];
  const float* b2 = (const float*)d_in[6];
  float* out = (float*)d_out;

  const int N = in_sizes[0] / 128;  // 65536 nodes
  const int E = in_sizes[2];        // 65536 edges
  const size_t NB = (size_t)N * 128;

  // workspace layout (no aliasing anywhere)
  f16* f0h       = (f16*)d_ws;              // [N,128] half feature buf A
  f16* f1h       = f0h + NB;                // [N,128] half feature buf B
  float* d_inv   = (float*)(f1h + NB);      // [N]
  float* e_scale = d_inv + N;               // [E]
  int* rp_e      = (int*)(e_scale + E);     // [E+1]
  int* rp_n      = rp_e + E + 1;            // [N+1]
  uint32* col_e  = (uint32*)(rp_n + N + 1); // [nnz]
  uint32* col_n  = col_e + nnz;             // [nnz]
  int* cnt_ce    = (int*)(col_n + nnz);     // [256]
  int* cnt_cn    = cnt_ce + 256;            // [256]
  int* base_e    = cnt_cn + 256;            // [257]
  int* base_n    = base_e + 257;            // [257]
  int* cur_e     = base_n + 257;            // [256]
  int* cur_n     = cur_e + 256;             // [256]
  f16* W1t       = (f16*)(cur_n + 256);     // [128,128] half W1^T
  f16* W2t       = W1t + 128 * 128;         // [128,128] half W2^T
  uint32* rec_e  = (uint32*)(W2t + 128 * 128);  // [nnz] dedicated
  uint32* rec_n  = rec_e + nnz;                 // [nnz] dedicated

  const int gemm_grid = N / 64;
  const int ga_grid = (N * 16) / 256;  // N == E

  // ---- weight prep + CSR build ----
  k_prep_w<<<8, 256, 0, stream>>>(W1, W2, W1t, W2t);
  hipMemsetAsync(cnt_ce, 0, 2 * 256 * sizeof(int), stream);
  k_passA<<<(nnz + 4095) / 4096, 256, 0, stream>>>(nidx, eidx, cnt_ce, cnt_cn, nnz);
  k_coarse_scan<<<1, 256, 0, stream>>>(cnt_ce, base_e, cur_e, cnt_cn, base_n, cur_n);
  k_passB<<<512, 256, 0, stream>>>(nidx, eidx, cur_e, cur_n, rec_e, rec_n, nnz);
  k_passC<<<512, 256, 0, stream>>>(rec_e, rec_n, base_e, base_n, w, rp_e, rp_n,
                                   col_e, col_n, e_scale, d_inv);

  // ---- layer 1 ----
  k_gemm<float><<<gemm_grid, 256, 0, stream>>>(x, W1t, f0h);   // f0h = half(x@W1)
  k_gather<<<ga_grid, 256, 0, stream>>>((const uint4*)f0h, f1h, rp_e, col_e,
                                        e_scale, nullptr, 0, 0, E);         // f1h = e_feat
  k_gather<<<ga_grid, 256, 0, stream>>>((const uint4*)f1h, f0h, rp_n, col_n,
                                        d_inv, b1, 1, 0, N);                // f0h = h

  // ---- layer 2 ----
  k_gemm<f16><<<gemm_grid, 256, 0, stream>>>(f0h, W2t, f1h);   // f1h = half(h@W2)
  k_gather<<<ga_grid, 256, 0, stream>>>((const uint4*)f1h, f0h, rp_e, col_e,
                                        e_scale, nullptr, 0, 0, E);         // f0h = e_feat
  k_gather<<<ga_grid, 256, 0, stream>>>((const uint4*)f0h, out, rp_n, col_n,
                                        d_inv, b2, 0, 1, N);                // out (fp32)
}

// Round 10
// 306.427 us; speedup vs baseline: 9.6415x; 1.0844x over previous
//
#include <hip/hip_runtime.h>
#include <hip/hip_fp16.h>

// ---------------------------------------------------------------------------
// HypergraphNet: out = conv2(relu(conv1(x)))
// conv(x) = D^-1 H diag(w) B^-1 H^T (x @ W) + b
// N = E = 65536, F = 128, nnz = 2^20.
//
// Round-9: R8 (hazard-hardened, passing) with the build head removed:
//   * fixed-capacity buckets (CAP=5120 >> 4096+16sigma) -> no passA, no
//     scan, no memset; cursors init'ed to b*CAP inside k_prep_w
//   * passB fuses both sides in one block pass: indices read ONCE per
//     launch (R8 invariant), both record streams emitted from registers
//   * passC reads strided segments [b*CAP, cur[b]); rp in b*257+i layout
//     (per-bucket end sentinel); col/rec stay uint32 word-granular,
//     dedicated workspace (R8 hardening kept)
// Pipeline (10 kernels):
//   k_prep_w  : W1,W2 -> half W^T [n][k]; bucket cursor init
//   k_passB   : single-read dual-side binning -> dense records
//   k_passC   : per-bucket finalize: rp, e_scale / d_inv, col
//   k_gemm<TA>: MFMA 16x16x32_f16
//   k_gather  : 16 lanes x 16B(half8) per row, unroll-4, fused
//               scale/bias/relu; half or fp32 output
// ---------------------------------------------------------------------------

typedef unsigned int uint32;
typedef _Float16 f16;
typedef _Float16 f16x8 __attribute__((ext_vector_type(8)));
typedef float f32x4 __attribute__((ext_vector_type(4)));

#define NBUK 256
#define BCAP 5120   // bucket capacity; mean 4096, sigma 64 -> 16 sigma slack

__global__ __launch_bounds__(256) void k_prep_w(const float* __restrict__ W1,
                                                const float* __restrict__ W2,
                                                f16* __restrict__ W1t,
                                                f16* __restrict__ W2t,
                                                int* __restrict__ cur_e,
                                                int* __restrict__ cur_n) {
  // bucket cursor init (blocks 0/1), fused with weight transpose
  if (blockIdx.x == 0) cur_e[threadIdx.x] = threadIdx.x * BCAP;
  if (blockIdx.x == 1) cur_n[threadIdx.x] = threadIdx.x * BCAP;
  const float* W = (blockIdx.x & 1) ? W2 : W1;
  f16* Wt = (blockIdx.x & 1) ? W2t : W1t;
  const int base = (blockIdx.x >> 1) * 4096;
#pragma unroll
  for (int it = 0; it < 16; ++it) {
    int idx = base + it * 256 + threadIdx.x;
    int k = idx >> 7, n = idx & 127;
    Wt[n * 128 + k] = (f16)W[k * 128 + n];
  }
}

// Bin entries of both sides into coarse buckets as packed records
// (keylow<<16 | value). Input read EXACTLY ONCE, cached in registers.
__global__ __launch_bounds__(256) void k_passB(const int* __restrict__ nidx,
                                               const int* __restrict__ eidx,
                                               int* __restrict__ cur_e,
                                               int* __restrict__ cur_n,
                                               uint32* __restrict__ rec_e,
                                               uint32* __restrict__ rec_n,
                                               int nnz) {
  __shared__ int hist_e[NBUK], hist_n[NBUK];
  __shared__ int gb_e[NBUK], gb_n[NBUK];
  __shared__ int lc_e[NBUK], lc_n[NBUK];
  const int tid = threadIdx.x;
  hist_e[tid] = 0;
  hist_n[tid] = 0;
  __syncthreads();
  int nk[16], ek[16];
  const int base = blockIdx.x * 4096;
#pragma unroll
  for (int it = 0; it < 16; ++it) {
    int i = base + it * 256 + tid;
    if (i < nnz) {
      nk[it] = nidx[i];
      ek[it] = eidx[i];
      atomicAdd(&hist_e[ek[it] >> 8], 1);
      atomicAdd(&hist_n[nk[it] >> 8], 1);
    } else {
      nk[it] = -1;
    }
  }
  __syncthreads();
  {
    int he = hist_e[tid], hn = hist_n[tid];
    gb_e[tid] = he ? atomicAdd(&cur_e[tid], he) : 0;
    gb_n[tid] = hn ? atomicAdd(&cur_n[tid], hn) : 0;
    lc_e[tid] = 0;
    lc_n[tid] = 0;
  }
  __syncthreads();
#pragma unroll
  for (int it = 0; it < 16; ++it) {
    if (nk[it] >= 0) {
      int de = ek[it] >> 8;
      int pe = atomicAdd(&lc_e[de], 1);
      rec_e[gb_e[de] + pe] = ((uint32)(ek[it] & 0xff) << 16) | (uint32)nk[it];
      int dn = nk[it] >> 8;
      int pn = atomicAdd(&lc_n[dn], 1);
      rec_n[gb_n[dn] + pn] = ((uint32)(nk[it] & 0xff) << 16) | (uint32)ek[it];
    }
  }
}

// Finalize one bucket: rp (b*257+i layout), scale, col (uint32).
// Bucket b's records live at [b*BCAP, cur[b]).
__global__ __launch_bounds__(256) void k_passC(const uint32* __restrict__ rec_e,
                                               const uint32* __restrict__ rec_n,
                                               const int* __restrict__ cur_e,
                                               const int* __restrict__ cur_n,
                                               const float* __restrict__ w,
                                               int* __restrict__ rp_e,
                                               int* __restrict__ rp_n,
                                               uint32* __restrict__ col_e,
                                               uint32* __restrict__ col_n,
                                               float* __restrict__ e_scale,
                                               float* __restrict__ d_inv) {
  __shared__ int hist[256];
  __shared__ int s[256];
  __shared__ int lcur[256];
  __shared__ float degf[256];
  const int tid = threadIdx.x;
  const int side = blockIdx.x >> 8;
  const int b = blockIdx.x & 255;
  const uint32* rec = side ? rec_n : rec_e;
  const int* cur = side ? cur_n : cur_e;
  int* rp = side ? rp_n : rp_e;
  uint32* col = side ? col_n : col_e;

  const int beg = b * BCAP, end = cur[b];
  hist[tid] = 0;
  degf[tid] = 0.f;
  __syncthreads();
  for (int j = beg + tid; j < end; j += 256) {
    uint32 r = rec[j];
    int d = r >> 16;
    atomicAdd(&hist[d], 1);
    if (side) atomicAdd(&degf[d], w[r & 0xffff]);
  }
  __syncthreads();
  int h = hist[tid];
  s[tid] = h;
  __syncthreads();
  for (int off = 1; off < 256; off <<= 1) {
    int t = (tid >= off) ? s[tid - off] : 0;
    __syncthreads();
    s[tid] += t;
    __syncthreads();
  }
  const int start = s[tid] - h;
  const int key = (b << 8) | tid;
  rp[b * 257 + tid] = beg + start;
  if (tid == 255) rp[b * 257 + 256] = end;
  if (side) {
    float d = degf[tid];
    d_inv[key] = d > 0.f ? 1.f / d : 0.f;
  } else {
    e_scale[key] = h > 0 ? w[key] / (float)h : 0.f;
  }
  lcur[tid] = start;
  __syncthreads();
  for (int j = beg + tid; j < end; j += 256) {
    uint32 r = rec[j];
    int d = r >> 16;
    int p = atomicAdd(&lcur[d], 1);
    col[beg + p] = r & 0xffffu;
  }
}

// C[M,128] = A[M,128] @ B[128,128] via MFMA f16, C stored half.
template <typename TA>
__global__ __launch_bounds__(256) void k_gemm(const TA* __restrict__ A,
                                              const f16* __restrict__ Bt,
                                              f16* __restrict__ C) {
  __shared__ f16 As[64][136];
  __shared__ f16 Bs[128][136];
  const int tid = threadIdx.x;
  const size_t m0 = (size_t)blockIdx.x * 64;

  {  // stage A: 4 threads/row, 32 halves each
    const int row = tid >> 2, seg = tid & 3;
    if constexpr (sizeof(TA) == 4) {
      const float4* ap = reinterpret_cast<const float4*>((const float*)A + (m0 + row) * 128 + seg * 32);
#pragma unroll
      for (int i = 0; i < 8; ++i) {
        float4 v = ap[i];
        union { f16 h[4]; uint2 u; } pk;
        pk.h[0] = (f16)v.x; pk.h[1] = (f16)v.y;
        pk.h[2] = (f16)v.z; pk.h[3] = (f16)v.w;
        *reinterpret_cast<uint2*>(&As[row][seg * 32 + i * 4]) = pk.u;
      }
    } else {
      const uint4* ap = reinterpret_cast<const uint4*>((const f16*)A + (m0 + row) * 128 + seg * 32);
#pragma unroll
      for (int i = 0; i < 4; ++i)
        *reinterpret_cast<uint4*>(&As[row][seg * 32 + i * 8]) = ap[i];
    }
  }
  {  // stage B: 2 threads/n-row, 64 halves each = 8 x uint4
    const int n = tid >> 1, seg = tid & 1;
    const uint4* bp = reinterpret_cast<const uint4*>(Bt + n * 128 + seg * 64);
#pragma unroll
    for (int i = 0; i < 8; ++i)
      *reinterpret_cast<uint4*>(&Bs[n][seg * 64 + i * 8]) = bp[i];
  }
  __syncthreads();

  const int wave = tid >> 6, lane = tid & 63;
  const int wm = wave >> 1, wn = wave & 1;
  const int fr = lane & 15, quad = lane >> 4;

  f32x4 acc[2][4];
#pragma unroll
  for (int i = 0; i < 2; ++i)
#pragma unroll
    for (int j = 0; j < 4; ++j) acc[i][j] = (f32x4){0.f, 0.f, 0.f, 0.f};

#pragma unroll
  for (int kk = 0; kk < 4; ++kk) {
    f16x8 af[2], bf[4];
#pragma unroll
    for (int i = 0; i < 2; ++i)
      af[i] = *reinterpret_cast<const f16x8*>(&As[wm * 32 + i * 16 + fr][kk * 32 + quad * 8]);
#pragma unroll
    for (int j = 0; j < 4; ++j)
      bf[j] = *reinterpret_cast<const f16x8*>(&Bs[wn * 64 + j * 16 + fr][kk * 32 + quad * 8]);
#pragma unroll
    for (int i = 0; i < 2; ++i)
#pragma unroll
      for (int j = 0; j < 4; ++j)
        acc[i][j] = __builtin_amdgcn_mfma_f32_16x16x32_f16(af[i], bf[j], acc[i][j], 0, 0, 0);
  }

  // C/D layout: col=lane&15, row=quad*4+reg (verified m89/m91)
#pragma unroll
  for (int i = 0; i < 2; ++i)
#pragma unroll
    for (int j = 0; j < 4; ++j)
#pragma unroll
      for (int r = 0; r < 4; ++r) {
        size_t row = m0 + wm * 32 + i * 16 + quad * 4 + r;
        int colc = wn * 64 + j * 16 + fr;
        C[row * 128 + colc] = (f16)acc[i][j][r];
      }
}

// 16 lanes x 16B (half8) per output row, unroll-4, fp32 accumulate.
// rp layout: beg = rp[(row>>8)*257 + (row&255)], end = next entry.
__global__ __launch_bounds__(256) void k_gather(const uint4* __restrict__ src,
                                                void* __restrict__ dst,
                                                const int* __restrict__ rp,
                                                const uint32* __restrict__ col,
                                                const float* __restrict__ rscale,
                                                const float* __restrict__ bias,
                                                int relu, int out_f32, int nrows) {
  const int row = (blockIdx.x * 256 + threadIdx.x) >> 4;
  const int lane = threadIdx.x & 15;
  if (row >= nrows) return;
  const int bidx = (row >> 8) * 257 + (row & 255);
  const int beg = rp[bidx], end = rp[bidx + 1];
  float acc[8];
#pragma unroll
  for (int k = 0; k < 8; ++k) acc[k] = 0.f;
  union U { uint4 u; f16 h[8]; };
  int j = beg;
  for (; j + 3 < end; j += 4) {
    uint32 c0 = col[j], c1 = col[j + 1], c2 = col[j + 2], c3 = col[j + 3];
    U v0, v1, v2, v3;
    v0.u = src[(size_t)c0 * 16 + lane];
    v1.u = src[(size_t)c1 * 16 + lane];
    v2.u = src[(size_t)c2 * 16 + lane];
    v3.u = src[(size_t)c3 * 16 + lane];
#pragma unroll
    for (int k = 0; k < 8; ++k)
      acc[k] += ((float)v0.h[k] + (float)v1.h[k]) + ((float)v2.h[k] + (float)v3.h[k]);
  }
  for (; j < end; ++j) {
    U v;
    v.u = src[(size_t)col[j] * 16 + lane];
#pragma unroll
    for (int k = 0; k < 8; ++k) acc[k] += (float)v.h[k];
  }
  const float s = rscale[row];
#pragma unroll
  for (int k = 0; k < 8; ++k) acc[k] *= s;
  if (bias) {
    const float4* bp = reinterpret_cast<const float4*>(bias) + lane * 2;
    float4 b0 = bp[0], b1 = bp[1];
    acc[0] += b0.x; acc[1] += b0.y; acc[2] += b0.z; acc[3] += b0.w;
    acc[4] += b1.x; acc[5] += b1.y; acc[6] += b1.z; acc[7] += b1.w;
    if (relu) {
#pragma unroll
      for (int k = 0; k < 8; ++k) acc[k] = fmaxf(acc[k], 0.f);
    }
  }
  if (out_f32) {
    float4* dp = (float4*)dst + (size_t)row * 32 + lane * 2;
    dp[0] = make_float4(acc[0], acc[1], acc[2], acc[3]);
    dp[1] = make_float4(acc[4], acc[5], acc[6], acc[7]);
  } else {
    U o;
#pragma unroll
    for (int k = 0; k < 8; ++k) o.h[k] = (f16)acc[k];
    ((uint4*)dst)[(size_t)row * 16 + lane] = o.u;
  }
}

extern "C" void kernel_launch(void* const* d_in, const int* in_sizes, int n_in,
                              void* d_out, int out_size, void* d_ws, size_t ws_size,
                              hipStream_t stream) {
  const float* x  = (const float*)d_in[0];
  const int* nidx = (const int*)d_in[1];
  const int nnz   = in_sizes[1] / 2;
  const int* eidx = nidx + nnz;
  const float* w  = (const float*)d_in[2];
  const float* W1 = (const float*)d_in[3];
  const float* b1 = (const float*)d_in[4];
  const float* W2 = (const float*)d_in[5];
  const float* b2 = (const float*)d_in[6];
  float* out = (float*)d_out;

  const int N = in_sizes[0] / 128;  // 65536 nodes
  const int E = in_sizes[2];        // 65536 edges
  const size_t NB = (size_t)N * 128;
  const size_t RCAP = (size_t)NBUK * BCAP;  // 1310720 slots per side

  // workspace layout (no aliasing anywhere)
  f16* f0h       = (f16*)d_ws;              // [N,128] half feature buf A
  f16* f1h       = f0h + NB;                // [N,128] half feature buf B
  float* d_inv   = (float*)(f1h + NB);      // [N]
  float* e_scale = d_inv + N;               // [E]
  int* rp_e      = (int*)(e_scale + E);     // [256*257]
  int* rp_n      = rp_e + NBUK * 257;       // [256*257]
  uint32* col_e  = (uint32*)(rp_n + NBUK * 257);  // [RCAP]
  uint32* col_n  = col_e + RCAP;            // [RCAP]
  int* cur_e     = (int*)(col_n + RCAP);    // [256]
  int* cur_n     = cur_e + 256;             // [256]
  f16* W1t       = (f16*)(cur_n + 256);     // [128,128] half W1^T
  f16* W2t       = W1t + 128 * 128;         // [128,128] half W2^T
  uint32* rec_e  = (uint32*)(W2t + 128 * 128);  // [RCAP] dedicated
  uint32* rec_n  = rec_e + RCAP;                // [RCAP] dedicated

  const int gemm_grid = N / 64;
  const int ga_grid = (N * 16) / 256;  // N == E

  // ---- weight prep (+ cursor init) + record build ----
  k_prep_w<<<8, 256, 0, stream>>>(W1, W2, W1t, W2t, cur_e, cur_n);
  k_passB<<<(nnz + 4095) / 4096, 256, 0, stream>>>(nidx, eidx, cur_e, cur_n,
                                                   rec_e, rec_n, nnz);
  k_passC<<<512, 256, 0, stream>>>(rec_e, rec_n, cur_e, cur_n, w, rp_e, rp_n,
                                   col_e, col_n, e_scale, d_inv);

  // ---- layer 1 ----
  k_gemm<float><<<gemm_grid, 256, 0, stream>>>(x, W1t, f0h);   // f0h = half(x@W1)
  k_gather<<<ga_grid, 256, 0, stream>>>((const uint4*)f0h, f1h, rp_e, col_e,
                                        e_scale, nullptr, 0, 0, E);         // f1h = e_feat
  k_gather<<<ga_grid, 256, 0, stream>>>((const uint4*)f1h, f0h, rp_n, col_n,
                                        d_inv, b1, 1, 0, N);                // f0h = h

  // ---- layer 2 ----
  k_gemm<f16><<<gemm_grid, 256, 0, stream>>>(f0h, W2t, f1h);   // f1h = half(h@W2)
  k_gather<<<ga_grid, 256, 0, stream>>>((const uint4*)f1h, f0h, rp_e, col_e,
                                        e_scale, nullptr, 0, 0, E);         // f0h = e_feat
  k_gather<<<ga_grid, 256, 0, stream>>>((const uint4*)f0h, out, rp_n, col_n,
                                        d_inv, b2, 0, 1, N);                // out (fp32)
}

// Round 11
// 296.537 us; speedup vs baseline: 9.9630x; 1.0334x over previous
//
#include <hip/hip_runtime.h>
#include <hip/hip_fp16.h>

// ---------------------------------------------------------------------------
// HypergraphNet: out = conv2(relu(conv1(x)))
// conv(x) = D^-1 H diag(w) B^-1 H^T (x @ W) + b
// N = E = 65536, F = 128, nnz = 2^20.
//
// Round-10: R9 + fusion of independent / producer-consumer stages.
//   * k_passC_gemm: passC (records staged in LDS, ONE global read) fused
//     with GEMM1 as extra blocks (independent work, MFMA hides under build)
//   * k_gngemm: gatherN1 fused with GEMM2 — block gathers its 64 node rows
//     (d_inv+b1+relu) straight into the MFMA As tile; h never materialized
//   * B-fragments read direct from global (W^T is 32KB, L2-hot) in both
//     fused kernels -> small LDS footprint
//   * all R8/R9 hazard hardening kept: uint32 col/rec, word-granular
//     single-writer cross-block stores, d_in read once per launch
// Launches (7): prep_w, passB, passC+GEMM1, gatherE1, gatherN1+GEMM2,
//               gatherE2, gatherN2
// ---------------------------------------------------------------------------

typedef unsigned int uint32;
typedef _Float16 f16;
typedef _Float16 f16x8 __attribute__((ext_vector_type(8)));
typedef float f32x4 __attribute__((ext_vector_type(4)));

#define NBUK 256
#define BCAP 5120   // bucket capacity; mean 4096, sigma 64 -> 16 sigma slack

__global__ __launch_bounds__(256) void k_prep_w(const float* __restrict__ W1,
                                                const float* __restrict__ W2,
                                                f16* __restrict__ W1t,
                                                f16* __restrict__ W2t,
                                                int* __restrict__ cur_e,
                                                int* __restrict__ cur_n) {
  if (blockIdx.x == 0) cur_e[threadIdx.x] = threadIdx.x * BCAP;
  if (blockIdx.x == 1) cur_n[threadIdx.x] = threadIdx.x * BCAP;
  const float* W = (blockIdx.x & 1) ? W2 : W1;
  f16* Wt = (blockIdx.x & 1) ? W2t : W1t;
  const int base = (blockIdx.x >> 1) * 4096;
#pragma unroll
  for (int it = 0; it < 16; ++it) {
    int idx = base + it * 256 + threadIdx.x;
    int k = idx >> 7, n = idx & 127;
    Wt[n * 128 + k] = (f16)W[k * 128 + n];
  }
}

// Bin entries of both sides into coarse buckets as packed records
// (keylow<<16 | value). Input read EXACTLY ONCE, cached in registers.
__global__ __launch_bounds__(256) void k_passB(const int* __restrict__ nidx,
                                               const int* __restrict__ eidx,
                                               int* __restrict__ cur_e,
                                               int* __restrict__ cur_n,
                                               uint32* __restrict__ rec_e,
                                               uint32* __restrict__ rec_n,
                                               int nnz) {
  __shared__ int hist_e[NBUK], hist_n[NBUK];
  __shared__ int gb_e[NBUK], gb_n[NBUK];
  __shared__ int lc_e[NBUK], lc_n[NBUK];
  const int tid = threadIdx.x;
  hist_e[tid] = 0;
  hist_n[tid] = 0;
  __syncthreads();
  int nk[16], ek[16];
  const int base = blockIdx.x * 4096;
#pragma unroll
  for (int it = 0; it < 16; ++it) {
    int i = base + it * 256 + tid;
    if (i < nnz) {
      nk[it] = nidx[i];
      ek[it] = eidx[i];
      atomicAdd(&hist_e[ek[it] >> 8], 1);
      atomicAdd(&hist_n[nk[it] >> 8], 1);
    } else {
      nk[it] = -1;
    }
  }
  __syncthreads();
  {
    int he = hist_e[tid], hn = hist_n[tid];
    gb_e[tid] = he ? atomicAdd(&cur_e[tid], he) : 0;
    gb_n[tid] = hn ? atomicAdd(&cur_n[tid], hn) : 0;
    lc_e[tid] = 0;
    lc_n[tid] = 0;
  }
  __syncthreads();
#pragma unroll
  for (int it = 0; it < 16; ++it) {
    if (nk[it] >= 0) {
      int de = ek[it] >> 8;
      int pe = atomicAdd(&lc_e[de], 1);
      rec_e[gb_e[de] + pe] = ((uint32)(ek[it] & 0xff) << 16) | (uint32)nk[it];
      int dn = nk[it] >> 8;
      int pn = atomicAdd(&lc_n[dn], 1);
      rec_n[gb_n[dn] + pn] = ((uint32)(nk[it] & 0xff) << 16) | (uint32)ek[it];
    }
  }
}

// Fused: blocks [0,512) finalize buckets (passC, records LDS-staged);
// blocks [512,1536) compute GEMM1: f0h = half(x @ W1) via MFMA, B direct
// from global. Independent work -> co-scheduled on the CUs.
__global__ __launch_bounds__(256) void k_passC_gemm(
    const uint32* __restrict__ rec_e, const uint32* __restrict__ rec_n,
    const int* __restrict__ cur_e, const int* __restrict__ cur_n,
    const float* __restrict__ w,
    int* __restrict__ rp_e, int* __restrict__ rp_n,
    uint32* __restrict__ col_e, uint32* __restrict__ col_n,
    float* __restrict__ e_scale, float* __restrict__ d_inv,
    const float* __restrict__ A, const f16* __restrict__ Bt,
    f16* __restrict__ C) {
  __shared__ __align__(16) char smem[BCAP * 4 + 4 * 256 * 4];  // 24576 B
  const int tid = threadIdx.x;

  if (blockIdx.x < 512) {
    // ---------------- passC path ----------------
    uint32* lrec = (uint32*)smem;                 // [BCAP]
    int* hist = (int*)(smem + BCAP * 4);          // [256]
    int* s = hist + 256;                          // [256]
    int* lcur = s + 256;                          // [256]
    float* degf = (float*)(lcur + 256);           // [256]
    const int side = blockIdx.x >> 8;
    const int b = blockIdx.x & 255;
    const uint32* rec = side ? rec_n : rec_e;
    const int* cur = side ? cur_n : cur_e;
    int* rp = side ? rp_n : rp_e;
    uint32* col = side ? col_n : col_e;

    const int beg = b * BCAP, end = cur[b];
    const int n = end - beg;
    hist[tid] = 0;
    degf[tid] = 0.f;
    __syncthreads();
    for (int j = tid; j < n; j += 256) lrec[j] = rec[beg + j];
    __syncthreads();
    for (int j = tid; j < n; j += 256) {
      uint32 r = lrec[j];
      int d = r >> 16;
      atomicAdd(&hist[d], 1);
      if (side) atomicAdd(&degf[d], w[r & 0xffff]);
    }
    __syncthreads();
    int h = hist[tid];
    s[tid] = h;
    __syncthreads();
    for (int off = 1; off < 256; off <<= 1) {
      int t = (tid >= off) ? s[tid - off] : 0;
      __syncthreads();
      s[tid] += t;
      __syncthreads();
    }
    const int start = s[tid] - h;
    const int key = (b << 8) | tid;
    rp[b * 257 + tid] = beg + start;
    if (tid == 255) rp[b * 257 + 256] = end;
    if (side) {
      float d = degf[tid];
      d_inv[key] = d > 0.f ? 1.f / d : 0.f;
    } else {
      e_scale[key] = h > 0 ? w[key] / (float)h : 0.f;
    }
    lcur[tid] = start;
    __syncthreads();
    for (int j = tid; j < n; j += 256) {
      uint32 r = lrec[j];
      int d = r >> 16;
      int p = atomicAdd(&lcur[d], 1);
      col[beg + p] = r & 0xffffu;
    }
  } else {
    // ---------------- GEMM1 path (A fp32, B direct from global) ----------
    f16(*As)[136] = (f16(*)[136])smem;            // [64][136] = 17408 B
    const size_t m0 = (size_t)(blockIdx.x - 512) * 64;
    {  // stage A: 4 threads/row, 32 halves each (fp32 -> f16)
      const int row = tid >> 2, seg = tid & 3;
      const float4* ap = reinterpret_cast<const float4*>(A + (m0 + row) * 128 + seg * 32);
#pragma unroll
      for (int i = 0; i < 8; ++i) {
        float4 v = ap[i];
        union { f16 h[4]; uint2 u; } pk;
        pk.h[0] = (f16)v.x; pk.h[1] = (f16)v.y;
        pk.h[2] = (f16)v.z; pk.h[3] = (f16)v.w;
        *reinterpret_cast<uint2*>(&As[row][seg * 32 + i * 4]) = pk.u;
      }
    }
    __syncthreads();
    const int wave = tid >> 6, lane = tid & 63;
    const int wm = wave >> 1, wn = wave & 1;
    const int fr = lane & 15, quad = lane >> 4;
    f32x4 acc[2][4];
#pragma unroll
    for (int i = 0; i < 2; ++i)
#pragma unroll
      for (int j = 0; j < 4; ++j) acc[i][j] = (f32x4){0.f, 0.f, 0.f, 0.f};
#pragma unroll
    for (int kk = 0; kk < 4; ++kk) {
      f16x8 af[2], bf[4];
#pragma unroll
      for (int i = 0; i < 2; ++i)
        af[i] = *reinterpret_cast<const f16x8*>(&As[wm * 32 + i * 16 + fr][kk * 32 + quad * 8]);
#pragma unroll
      for (int j = 0; j < 4; ++j)
        bf[j] = *reinterpret_cast<const f16x8*>(Bt + (wn * 64 + j * 16 + fr) * 128 + kk * 32 + quad * 8);
#pragma unroll
      for (int i = 0; i < 2; ++i)
#pragma unroll
        for (int j = 0; j < 4; ++j)
          acc[i][j] = __builtin_amdgcn_mfma_f32_16x16x32_f16(af[i], bf[j], acc[i][j], 0, 0, 0);
    }
    // C/D layout: col=lane&15, row=quad*4+reg
#pragma unroll
    for (int i = 0; i < 2; ++i)
#pragma unroll
      for (int j = 0; j < 4; ++j)
#pragma unroll
        for (int r = 0; r < 4; ++r) {
          size_t row = m0 + wm * 32 + i * 16 + quad * 4 + r;
          int colc = wn * 64 + j * 16 + fr;
          C[row * 128 + colc] = (f16)acc[i][j][r];
        }
  }
}

// Fused gatherN + GEMM: block b gathers node rows [64b, 64b+64) from src
// (e_feat) with d_inv+bias+relu, writes them as f16 into the MFMA As tile,
// then computes C[64 rows] = As @ W^T (B direct from global). h is never
// materialized to global.
__global__ __launch_bounds__(256) void k_gngemm(const uint4* __restrict__ src,
                                                const int* __restrict__ rp,
                                                const uint32* __restrict__ col,
                                                const float* __restrict__ d_inv,
                                                const float* __restrict__ bias,
                                                const f16* __restrict__ Bt,
                                                f16* __restrict__ C) {
  __shared__ f16 As[64][136];
  const int tid = threadIdx.x;
  const int b = blockIdx.x;
  const int g = tid >> 4, l = tid & 15;

  // ---- gather phase: 4 passes x 16 rows ----
  union U { uint4 u; f16 h[8]; };
#pragma unroll
  for (int p = 0; p < 4; ++p) {
    const int rl = p * 16 + g;
    const int row = b * 64 + rl;
    const int bidx = (row >> 8) * 257 + (row & 255);
    const int beg = rp[bidx], end = rp[bidx + 1];
    float acc[8];
#pragma unroll
    for (int k = 0; k < 8; ++k) acc[k] = 0.f;
    int j = beg;
    for (; j + 3 < end; j += 4) {
      uint32 c0 = col[j], c1 = col[j + 1], c2 = col[j + 2], c3 = col[j + 3];
      U v0, v1, v2, v3;
      v0.u = src[(size_t)c0 * 16 + l];
      v1.u = src[(size_t)c1 * 16 + l];
      v2.u = src[(size_t)c2 * 16 + l];
      v3.u = src[(size_t)c3 * 16 + l];
#pragma unroll
      for (int k = 0; k < 8; ++k)
        acc[k] += ((float)v0.h[k] + (float)v1.h[k]) + ((float)v2.h[k] + (float)v3.h[k]);
    }
    for (; j < end; ++j) {
      U v;
      v.u = src[(size_t)col[j] * 16 + l];
#pragma unroll
      for (int k = 0; k < 8; ++k) acc[k] += (float)v.h[k];
    }
    const float sc = d_inv[row];
    const float4* bp = reinterpret_cast<const float4*>(bias) + l * 2;
    float4 b0 = bp[0], b1 = bp[1];
    acc[0] = fmaxf(acc[0] * sc + b0.x, 0.f);
    acc[1] = fmaxf(acc[1] * sc + b0.y, 0.f);
    acc[2] = fmaxf(acc[2] * sc + b0.z, 0.f);
    acc[3] = fmaxf(acc[3] * sc + b0.w, 0.f);
    acc[4] = fmaxf(acc[4] * sc + b1.x, 0.f);
    acc[5] = fmaxf(acc[5] * sc + b1.y, 0.f);
    acc[6] = fmaxf(acc[6] * sc + b1.z, 0.f);
    acc[7] = fmaxf(acc[7] * sc + b1.w, 0.f);
    U o;
#pragma unroll
    for (int k = 0; k < 8; ++k) o.h[k] = (f16)acc[k];
    *reinterpret_cast<uint4*>(&As[rl][l * 8]) = o.u;
  }
  __syncthreads();

  // ---- MFMA phase ----
  const int wave = tid >> 6, lane = tid & 63;
  const int wm = wave >> 1, wn = wave & 1;
  const int fr = lane & 15, quad = lane >> 4;
  const size_t m0 = (size_t)b * 64;
  f32x4 acc[2][4];
#pragma unroll
  for (int i = 0; i < 2; ++i)
#pragma unroll
    for (int j = 0; j < 4; ++j) acc[i][j] = (f32x4){0.f, 0.f, 0.f, 0.f};
#pragma unroll
  for (int kk = 0; kk < 4; ++kk) {
    f16x8 af[2], bf[4];
#pragma unroll
    for (int i = 0; i < 2; ++i)
      af[i] = *reinterpret_cast<const f16x8*>(&As[wm * 32 + i * 16 + fr][kk * 32 + quad * 8]);
#pragma unroll
    for (int j = 0; j < 4; ++j)
      bf[j] = *reinterpret_cast<const f16x8*>(Bt + (wn * 64 + j * 16 + fr) * 128 + kk * 32 + quad * 8);
#pragma unroll
    for (int i = 0; i < 2; ++i)
#pragma unroll
      for (int j = 0; j < 4; ++j)
        acc[i][j] = __builtin_amdgcn_mfma_f32_16x16x32_f16(af[i], bf[j], acc[i][j], 0, 0, 0);
  }
#pragma unroll
  for (int i = 0; i < 2; ++i)
#pragma unroll
    for (int j = 0; j < 4; ++j)
#pragma unroll
      for (int r = 0; r < 4; ++r) {
        size_t row = m0 + wm * 32 + i * 16 + quad * 4 + r;
        int colc = wn * 64 + j * 16 + fr;
        C[row * 128 + colc] = (f16)acc[i][j][r];
      }
}

// 16 lanes x 16B (half8) per output row, unroll-4, fp32 accumulate.
// rp layout: beg = rp[(row>>8)*257 + (row&255)], end = next entry.
__global__ __launch_bounds__(256) void k_gather(const uint4* __restrict__ src,
                                                void* __restrict__ dst,
                                                const int* __restrict__ rp,
                                                const uint32* __restrict__ col,
                                                const float* __restrict__ rscale,
                                                const float* __restrict__ bias,
                                                int relu, int out_f32, int nrows) {
  const int row = (blockIdx.x * 256 + threadIdx.x) >> 4;
  const int lane = threadIdx.x & 15;
  if (row >= nrows) return;
  const int bidx = (row >> 8) * 257 + (row & 255);
  const int beg = rp[bidx], end = rp[bidx + 1];
  float acc[8];
#pragma unroll
  for (int k = 0; k < 8; ++k) acc[k] = 0.f;
  union U { uint4 u; f16 h[8]; };
  int j = beg;
  for (; j + 3 < end; j += 4) {
    uint32 c0 = col[j], c1 = col[j + 1], c2 = col[j + 2], c3 = col[j + 3];
    U v0, v1, v2, v3;
    v0.u = src[(size_t)c0 * 16 + lane];
    v1.u = src[(size_t)c1 * 16 + lane];
    v2.u = src[(size_t)c2 * 16 + lane];
    v3.u = src[(size_t)c3 * 16 + lane];
#pragma unroll
    for (int k = 0; k < 8; ++k)
      acc[k] += ((float)v0.h[k] + (float)v1.h[k]) + ((float)v2.h[k] + (float)v3.h[k]);
  }
  for (; j < end; ++j) {
    U v;
    v.u = src[(size_t)col[j] * 16 + lane];
#pragma unroll
    for (int k = 0; k < 8; ++k) acc[k] += (float)v.h[k];
  }
  const float s = rscale[row];
#pragma unroll
  for (int k = 0; k < 8; ++k) acc[k] *= s;
  if (bias) {
    const float4* bp = reinterpret_cast<const float4*>(bias) + lane * 2;
    float4 b0 = bp[0], b1 = bp[1];
    acc[0] += b0.x; acc[1] += b0.y; acc[2] += b0.z; acc[3] += b0.w;
    acc[4] += b1.x; acc[5] += b1.y; acc[6] += b1.z; acc[7] += b1.w;
    if (relu) {
#pragma unroll
      for (int k = 0; k < 8; ++k) acc[k] = fmaxf(acc[k], 0.f);
    }
  }
  if (out_f32) {
    float4* dp = (float4*)dst + (size_t)row * 32 + lane * 2;
    dp[0] = make_float4(acc[0], acc[1], acc[2], acc[3]);
    dp[1] = make_float4(acc[4], acc[5], acc[6], acc[7]);
  } else {
    U o;
#pragma unroll
    for (int k = 0; k < 8; ++k) o.h[k] = (f16)acc[k];
    ((uint4*)dst)[(size_t)row * 16 + lane] = o.u;
  }
}

extern "C" void kernel_launch(void* const* d_in, const int* in_sizes, int n_in,
                              void* d_out, int out_size, void* d_ws, size_t ws_size,
                              hipStream_t stream) {
  const float* x  = (const float*)d_in[0];
  const int* nidx = (const int*)d_in[1];
  const int nnz   = in_sizes[1] / 2;
  const int* eidx = nidx + nnz;
  const float* w  = (const float*)d_in[2];
  const float* W1 = (const float*)d_in[3];
  const float* b1 = (const float*)d_in[4];
  const float* W2 = (const float*)d_in[5];
  const float* b2 = (const float*)d_in[6];
  float* out = (float*)d_out;

  const int N = in_sizes[0] / 128;  // 65536 nodes
  const int E = in_sizes[2];        // 65536 edges
  const size_t NB = (size_t)N * 128;
  const size_t RCAP = (size_t)NBUK * BCAP;  // 1310720 slots per side

  // workspace layout (no aliasing anywhere)
  f16* f0h       = (f16*)d_ws;              // [N,128] half feature buf A
  f16* f1h       = f0h + NB;                // [N,128] half feature buf B
  float* d_inv   = (float*)(f1h + NB);      // [N]
  float* e_scale = d_inv + N;               // [E]
  int* rp_e      = (int*)(e_scale + E);     // [256*257]
  int* rp_n      = rp_e + NBUK * 257;       // [256*257]
  uint32* col_e  = (uint32*)(rp_n + NBUK * 257);  // [RCAP]
  uint32* col_n  = col_e + RCAP;            // [RCAP]
  int* cur_e     = (int*)(col_n + RCAP);    // [256]
  int* cur_n     = cur_e + 256;             // [256]
  f16* W1t       = (f16*)(cur_n + 256);     // [128,128] half W1^T
  f16* W2t       = W1t + 128 * 128;         // [128,128] half W2^T
  uint32* rec_e  = (uint32*)(W2t + 128 * 128);  // [RCAP] dedicated
  uint32* rec_n  = rec_e + RCAP;                // [RCAP] dedicated

  const int ga_grid = (N * 16) / 256;  // N == E

  // ---- build ----
  k_prep_w<<<8, 256, 0, stream>>>(W1, W2, W1t, W2t, cur_e, cur_n);
  k_passB<<<(nnz + 4095) / 4096, 256, 0, stream>>>(nidx, eidx, cur_e, cur_n,
                                                   rec_e, rec_n, nnz);
  // passC (512 blocks) + GEMM1 (1024 blocks): f0h = half(x@W1)
  k_passC_gemm<<<1536, 256, 0, stream>>>(rec_e, rec_n, cur_e, cur_n, w,
                                         rp_e, rp_n, col_e, col_n,
                                         e_scale, d_inv, x, W1t, f0h);

  // ---- layer 1 + GEMM2 ----
  k_gather<<<ga_grid, 256, 0, stream>>>((const uint4*)f0h, f1h, rp_e, col_e,
                                        e_scale, nullptr, 0, 0, E);   // f1h = e_feat
  // gatherN1 (d_inv,b1,relu) fused with GEMM2: f0h = half(h@W2), h in LDS only
  k_gngemm<<<N / 64, 256, 0, stream>>>((const uint4*)f1h, rp_n, col_n,
                                       d_inv, b1, W2t, f0h);

  // ---- layer 2 ----
  k_gather<<<ga_grid, 256, 0, stream>>>((const uint4*)f0h, f1h, rp_e, col_e,
                                        e_scale, nullptr, 0, 0, E);   // f1h = e_feat
  k_gather<<<ga_grid, 256, 0, stream>>>((const uint4*)f1h, out, rp_n, col_n,
                                        d_inv, b2, 0, 1, N);          // out (fp32)
}